// Round 2
// baseline (116.659 us; speedup 1.0000x reference)
//
#include <hip/hip_runtime.h>

// out[row][k] = x[row][k] * Lambda[k] + sum_l B[k][l] * y[row][l]
// rows = 1,048,576 ; L = 32.
// 16 lanes per row; lane s = tid&15 owns outputs k = 2s, 2s+1.
// Per-lane B footprint: 2 rows of B = 64 floats (32 VGPR pairs) -> stays
// register-resident under the 128-VGPR cap from __launch_bounds__(256,4).
// y pairs exchanged within the 16-lane group via __shfl width=16.

__global__ __launch_bounds__(256, 4) void ax_bu_kernel(
    const float* __restrict__ x,
    const float* __restrict__ y,
    const float* __restrict__ Lam,
    const float* __restrict__ B,
    float* __restrict__ out,
    int n2)   // total float2 count = rows * 16
{
    const int s = threadIdx.x & 15;
    const float2 lam = reinterpret_cast<const float2*>(Lam)[s];
    const float2* __restrict__ B2 = reinterpret_cast<const float2*>(B);

    // B[2s][l] and B[2s+1][l] as float2 pairs over l -> 64 floats in VGPRs
    float2 B0[16], B1[16];
#pragma unroll
    for (int g = 0; g < 16; ++g) {
        B0[g] = B2[(2 * s) * 16 + g];
        B1[g] = B2[(2 * s + 1) * 16 + g];
    }

    const float2* __restrict__ x2 = reinterpret_cast<const float2*>(x);
    const float2* __restrict__ y2 = reinterpret_cast<const float2*>(y);
    float2* __restrict__ o2 = reinterpret_cast<float2*>(out);

    const int stride = gridDim.x * blockDim.x;
    int t = blockIdx.x * blockDim.x + threadIdx.x;
    if (t >= n2) return;

    float2 xv = x2[t];
    float2 yv = y2[t];

    while (true) {
        const int tn = t + stride;
        const bool more = (tn < n2);
        float2 xn, yn;
        if (more) { xn = x2[tn]; yn = y2[tn]; }   // prefetch next tile

        float a0 = xv.x * lam.x;
        float a1 = xv.y * lam.y;

#pragma unroll
        for (int g = 0; g < 16; ++g) {
            const float b0 = __shfl(yv.x, g, 16);   // y[2g]
            const float b1 = __shfl(yv.y, g, 16);   // y[2g+1]
            a0 = fmaf(B0[g].x, b0, a0);
            a0 = fmaf(B0[g].y, b1, a0);
            a1 = fmaf(B1[g].x, b0, a1);
            a1 = fmaf(B1[g].y, b1, a1);
        }

        o2[t] = make_float2(a0, a1);

        if (!more) break;
        xv = xn; yv = yn; t = tn;
    }
}

extern "C" void kernel_launch(void* const* d_in, const int* in_sizes, int n_in,
                              void* d_out, int out_size, void* d_ws, size_t ws_size,
                              hipStream_t stream) {
    const float* x   = (const float*)d_in[0];
    const float* y   = (const float*)d_in[1];
    const float* Lam = (const float*)d_in[2];
    const float* B   = (const float*)d_in[3];
    float* out = (float*)d_out;

    const int n2 = in_sizes[0] / 2;          // 16,777,216 float2 elements
    const int block = 256;
    int grid = 2048;                          // 524,288 threads; 32 iters/thread
    if (grid * block > n2) grid = (n2 + block - 1) / block;

    ax_bu_kernel<<<grid, block, 0, stream>>>(x, y, Lam, B, out, n2);
}

// Round 3
// 113.308 us; speedup vs baseline: 1.0296x; 1.0296x over previous
//
#include <hip/hip_runtime.h>

// out[row][k] = x[row][k] * Lambda[k] + sum_l B[k][l] * y[row][l]
// rows = b*c*h*w*n = 1,048,576 ; L = 32.
// 8 lanes per row; lane owns quad q = lane&7 -> outputs k = 4q..4q+3.
// B rows for those outputs (128 floats) are loaded once and PINNED into
// VGPRs with opaque asm (the compiler otherwise sinks/remats the loads
// into the loop -> 32 L1 loads/lane/iter, which was R1/R2's bottleneck:
// VGPR_Count came back 96/64, far below the B footprint).
// y quads exchanged within the 8-lane group via __shfl width=8 (DS pipe).

#define PIN(v) asm volatile("" : "+v"(v))

__global__ __launch_bounds__(256) void ax_bu_kernel(
    const float* __restrict__ x,
    const float* __restrict__ y,
    const float* __restrict__ Lam,
    const float* __restrict__ B,
    float* __restrict__ out,
    int n4)   // total float4 count = rows * 8
{
    const int q = threadIdx.x & 7;
    const float4 lam = reinterpret_cast<const float4*>(Lam)[q];

    // B[k][l], k = q*4+m, as 8 float4 per output row -> 32 float4 = 128 VGPRs
    float4 Bv[4][8];
#pragma unroll
    for (int m = 0; m < 4; ++m)
#pragma unroll
        for (int g = 0; g < 8; ++g)
            Bv[m][g] = reinterpret_cast<const float4*>(B)[(q * 4 + m) * 8 + g];

    // Pin every component: opaque redefinition -> loads cannot be sunk/remat'd.
#pragma unroll
    for (int m = 0; m < 4; ++m)
#pragma unroll
        for (int g = 0; g < 8; ++g) {
            PIN(Bv[m][g].x); PIN(Bv[m][g].y); PIN(Bv[m][g].z); PIN(Bv[m][g].w);
        }

    const float4* __restrict__ x4 = reinterpret_cast<const float4*>(x);
    const float4* __restrict__ y4 = reinterpret_cast<const float4*>(y);
    float4* __restrict__ o4 = reinterpret_cast<float4*>(out);

    const int stride = gridDim.x * blockDim.x;
    int t = blockIdx.x * blockDim.x + threadIdx.x;
    if (t >= n4) return;

    float4 xv = x4[t];
    float4 yv = y4[t];

    while (true) {
        const int tn = t + stride;
        const bool more = (tn < n4);
        float4 xn, yn;
        if (more) { xn = x4[tn]; yn = y4[tn]; }   // prefetch next tile

        float acc0 = xv.x * lam.x;
        float acc1 = xv.y * lam.y;
        float acc2 = xv.z * lam.z;
        float acc3 = xv.w * lam.w;

#pragma unroll
        for (int g = 0; g < 8; ++g) {
            const float b0 = __shfl(yv.x, g, 8);
            const float b1 = __shfl(yv.y, g, 8);
            const float b2 = __shfl(yv.z, g, 8);
            const float b3 = __shfl(yv.w, g, 8);

            acc0 = fmaf(Bv[0][g].x, b0, acc0);
            acc0 = fmaf(Bv[0][g].y, b1, acc0);
            acc0 = fmaf(Bv[0][g].z, b2, acc0);
            acc0 = fmaf(Bv[0][g].w, b3, acc0);

            acc1 = fmaf(Bv[1][g].x, b0, acc1);
            acc1 = fmaf(Bv[1][g].y, b1, acc1);
            acc1 = fmaf(Bv[1][g].z, b2, acc1);
            acc1 = fmaf(Bv[1][g].w, b3, acc1);

            acc2 = fmaf(Bv[2][g].x, b0, acc2);
            acc2 = fmaf(Bv[2][g].y, b1, acc2);
            acc2 = fmaf(Bv[2][g].z, b2, acc2);
            acc2 = fmaf(Bv[2][g].w, b3, acc2);

            acc3 = fmaf(Bv[3][g].x, b0, acc3);
            acc3 = fmaf(Bv[3][g].y, b1, acc3);
            acc3 = fmaf(Bv[3][g].z, b2, acc3);
            acc3 = fmaf(Bv[3][g].w, b3, acc3);
        }

        o4[t] = make_float4(acc0, acc1, acc2, acc3);

        if (!more) break;
        xv = xn; yv = yn; t = tn;
    }
}

extern "C" void kernel_launch(void* const* d_in, const int* in_sizes, int n_in,
                              void* d_out, int out_size, void* d_ws, size_t ws_size,
                              hipStream_t stream) {
    const float* x   = (const float*)d_in[0];
    const float* y   = (const float*)d_in[1];
    const float* Lam = (const float*)d_in[2];
    const float* B   = (const float*)d_in[3];
    float* out = (float*)d_out;

    const int n4 = in_sizes[0] / 4;          // 8,388,608 float4 elements
    const int block = 256;
    int grid = 2048;                          // 524,288 threads; 16 iters/thread
    if (grid * block > n4) grid = (n4 + block - 1) / block;

    ax_bu_kernel<<<grid, block, 0, stream>>>(x, y, Lam, B, out, n4);
}

// Round 4
// 80.767 us; speedup vs baseline: 1.4444x; 1.4029x over previous
//
#include <hip/hip_runtime.h>

// out[row][k] = x[row][k]*Lambda[k] + sum_l B[k][l]*y[row][l]
// rows = 1,048,576, L = 32.  This is a skinny GEMM: out = x.lam + y * B^T,
// M = rows, K = N = 32.  Use mfma_f32_16x16x32_bf16 with C-in = x*lam (fp32,
// exact); y and B are cast to bf16 (absmax threshold 0.74 >> bf16 error).
//
// Per 16-row tile per wave:
//   A-frag  : y[row0+(lane&15)][(lane>>4)*8 + j], j=0..7  (bf16x8)
//   B-frag  : Bt[k][col] = B[col][k] -> lane reads CONTIGUOUS
//             B[(lane&15)+ctile*16][(lane>>4)*8 + j]      (hoisted, 8 VGPRs)
//   C/D     : col = lane&15 (+16 for tile1), row = row0 + (lane>>4)*4 + reg
// No LDS, no shfl, no per-lane B array -> nothing for regalloc to spill.

typedef __attribute__((ext_vector_type(8))) short bf16x8;
typedef __attribute__((ext_vector_type(4))) float f32x4;

__device__ __forceinline__ short f2bf(float f) {
    union { float f; unsigned u; } v; v.f = f;
    unsigned r = v.u + 0x7fffu + ((v.u >> 16) & 1u);   // RNE (inputs are finite)
    return (short)(r >> 16);
}

__global__ __launch_bounds__(256) void ax_bu_mfma(
    const float* __restrict__ x,
    const float* __restrict__ y,
    const float* __restrict__ Lam,
    const float* __restrict__ B,
    float* __restrict__ out,
    int ntiles)   // rows / 16
{
    const int lane = threadIdx.x & 63;
    const int gw = (blockIdx.x * (blockDim.x >> 6)) + (threadIdx.x >> 6);
    const int nwaves = gridDim.x * (blockDim.x >> 6);

    const int r = lane & 15;   // 16-dim index (A row / B col / C col)
    const int h = lane >> 4;   // k-octet selector / C row-quad selector

    // Hoisted B-frags: Bt[k = h*8+j][col = r (+16)] = B[r (+16)][h*8+j]
    bf16x8 bf0, bf1;
    {
        const float* b0 = B + r * 32 + h * 8;
        const float* b1 = B + (r + 16) * 32 + h * 8;
#pragma unroll
        for (int j = 0; j < 8; ++j) {
            bf0[j] = f2bf(b0[j]);
            bf1[j] = f2bf(b1[j]);
        }
    }
    const float lam0 = Lam[r];
    const float lam1 = Lam[r + 16];

    for (int t = gw; t < ntiles; t += nwaves) {
        const int row0 = t << 4;

        // A-frag: y[row0 + r][h*8 .. h*8+7] (two float4 loads, convert)
        const float4* ya = reinterpret_cast<const float4*>(y + (row0 + r) * 32 + h * 8);
        const float4 y0 = ya[0];
        const float4 y1 = ya[1];
        bf16x8 af;
        af[0] = f2bf(y0.x); af[1] = f2bf(y0.y); af[2] = f2bf(y0.z); af[3] = f2bf(y0.w);
        af[4] = f2bf(y1.x); af[5] = f2bf(y1.y); af[6] = f2bf(y1.z); af[7] = f2bf(y1.w);

        // C-in = x * lam (fp32 exact), C layout: row = row0 + h*4 + j, col = r (+16)
        f32x4 c0, c1;
#pragma unroll
        for (int j = 0; j < 4; ++j) {
            const int rr = row0 + h * 4 + j;
            c0[j] = x[rr * 32 + r]      * lam0;
            c1[j] = x[rr * 32 + r + 16] * lam1;
        }

        c0 = __builtin_amdgcn_mfma_f32_16x16x32_bf16(af, bf0, c0, 0, 0, 0);
        c1 = __builtin_amdgcn_mfma_f32_16x16x32_bf16(af, bf1, c1, 0, 0, 0);

#pragma unroll
        for (int j = 0; j < 4; ++j) {
            const int rr = row0 + h * 4 + j;
            out[rr * 32 + r]      = c0[j];
            out[rr * 32 + r + 16] = c1[j];
        }
    }
}

extern "C" void kernel_launch(void* const* d_in, const int* in_sizes, int n_in,
                              void* d_out, int out_size, void* d_ws, size_t ws_size,
                              hipStream_t stream) {
    const float* x   = (const float*)d_in[0];
    const float* y   = (const float*)d_in[1];
    const float* Lam = (const float*)d_in[2];
    const float* B   = (const float*)d_in[3];
    float* out = (float*)d_out;

    const int rows = in_sizes[0] / 32;       // 1,048,576
    const int ntiles = rows / 16;            // 65,536
    const int block = 256;                   // 4 waves
    int grid = 2048;                         // 8192 waves -> 8 tiles/wave
    if (grid * (block >> 6) > ntiles) grid = (ntiles + (block >> 6) - 1) / (block >> 6);

    ax_bu_mfma<<<grid, block, 0, stream>>>(x, y, Lam, B, out, ntiles);
}